// Round 4
// baseline (746.978 us; speedup 1.0000x reference)
//
#include <hip/hip_runtime.h>
#include <hip/hip_bf16.h>
#include <math.h>

#define SDIM 512
#define BDIM 64
#define HDIM 512
#define TDIM 32

constexpr int BM = 128, BN = 64, KT = 16;

// static scratch: no dependence on d_ws / ws_size
__device__ float g_em[SDIM * BDIM * TDIM];  // 4 MB, fully overwritten each call

// ---------------- Fused emissions kernel ----------------
// emissions[s,b,t] = sigmoid(hidden[s,b,:] @ W1 + b1) @ W2 + b2
// static LDS: As 8K + Bs 4K + H1 34.8K + W2cT 8.7K = 55.8 KB (< 64 KB)
__global__ __launch_bounds__(256, 1) void emis_kernel(
    const float* __restrict__ hidden, const float* __restrict__ W1,
    const float* __restrict__ b1, const float* __restrict__ W2,
    const float* __restrict__ b2)
{
  __shared__ float As[KT][BM];          // As[k][r]
  __shared__ float Bs[KT][BN];          // Bs[k][c]
  __shared__ float H1[BM][BN + 4];      // sigmoid tile
  __shared__ float W2cT[TDIM][BN + 4];  // W2 chunk transposed

  const int tid = threadIdx.x;
  const int row0 = blockIdx.x * BM;
  const int trg = tid & 15;   // row group
  const int tcg = tid >> 4;   // col group
  const int tx = tid & 31;    // tag
  const int ty = tid >> 5;    // row sub

  float eacc[16];
#pragma unroll
  for (int k = 0; k < 16; ++k) eacc[k] = 0.f;

  for (int jc = 0; jc < HDIM; jc += BN) {
    // stage W2 chunk transposed: W2cT[t][j] = W2[(jc+j)*T + t]
#pragma unroll
    for (int i = 0; i < 8; ++i) {
      int e = tid + 256 * i;           // 0..2047
      int j = e >> 5, t = e & 31;
      W2cT[t][j] = W2[(size_t)(jc + j) * TDIM + t];
    }

    float acc[2][4][4];
#pragma unroll
    for (int a = 0; a < 2; ++a)
#pragma unroll
      for (int i = 0; i < 4; ++i)
#pragma unroll
        for (int j = 0; j < 4; ++j) acc[a][i][j] = 0.f;

    for (int k0 = 0; k0 < HDIM; k0 += KT) {
      // As[k][r] <- hidden[row0+r][k0+k]
#pragma unroll
      for (int i = 0; i < 2; ++i) {
        int f4 = tid + 256 * i;        // 0..511
        int r = f4 >> 2, q = f4 & 3;
        float4 v = *(const float4*)&hidden[(size_t)(row0 + r) * HDIM + k0 + 4 * q];
        As[4 * q + 0][r] = v.x;
        As[4 * q + 1][r] = v.y;
        As[4 * q + 2][r] = v.z;
        As[4 * q + 3][r] = v.w;
      }
      // Bs[k][c] <- W1[k0+k][jc+c]
      {
        int k = tid >> 4, c4 = tid & 15;
        *(float4*)&Bs[k][4 * c4] =
            *(const float4*)&W1[(size_t)(k0 + k) * HDIM + jc + 4 * c4];
      }
      __syncthreads();
#pragma unroll
      for (int kk = 0; kk < KT; ++kk) {
        float4 a0 = *(const float4*)&As[kk][4 * trg];
        float4 a1 = *(const float4*)&As[kk][64 + 4 * trg];
        float4 w0 = *(const float4*)&Bs[kk][4 * tcg];
        float av[2][4] = {{a0.x, a0.y, a0.z, a0.w}, {a1.x, a1.y, a1.z, a1.w}};
        float bw[4] = {w0.x, w0.y, w0.z, w0.w};
#pragma unroll
        for (int ri = 0; ri < 2; ++ri)
#pragma unroll
          for (int i = 0; i < 4; ++i)
#pragma unroll
            for (int j = 0; j < 4; ++j)
              acc[ri][i][j] = fmaf(av[ri][i], bw[j], acc[ri][i][j]);
      }
      __syncthreads();
    }

    // bias + sigmoid -> H1
    {
      float4 bias = *(const float4*)&b1[jc + 4 * tcg];
      float bb[4] = {bias.x, bias.y, bias.z, bias.w};
#pragma unroll
      for (int ri = 0; ri < 2; ++ri)
#pragma unroll
        for (int i = 0; i < 4; ++i) {
          float4 h;
          h.x = 1.f / (1.f + expf(-(acc[ri][i][0] + bb[0])));
          h.y = 1.f / (1.f + expf(-(acc[ri][i][1] + bb[1])));
          h.z = 1.f / (1.f + expf(-(acc[ri][i][2] + bb[2])));
          h.w = 1.f / (1.f + expf(-(acc[ri][i][3] + bb[3])));
          *(float4*)&H1[ri * 64 + 4 * trg + i][4 * tcg] = h;
        }
    }
    __syncthreads();

    // eacc[k] += sum_j H1[ty+8k][j] * W2cT[tx][j]
#pragma unroll
    for (int jq = 0; jq < BN / 4; ++jq) {
      float4 w = *(const float4*)&W2cT[tx][4 * jq];
#pragma unroll
      for (int k = 0; k < 16; ++k) {
        float4 h = *(const float4*)&H1[ty + 8 * k][4 * jq];
        eacc[k] = fmaf(h.x, w.x, fmaf(h.y, w.y, fmaf(h.z, w.z, fmaf(h.w, w.w, eacc[k]))));
      }
    }
    __syncthreads();
  }

#pragma unroll
  for (int k = 0; k < 16; ++k) {
    g_em[(size_t)(row0 + ty + 8 * k) * TDIM + tx] = eacc[k] + b2[tx];
  }
}

// ---------------- Viterbi kernel (1 wave / batch) ----------------
__global__ __launch_bounds__(64, 1) void viterbi_kernel(
    const int* __restrict__ lens, const float* __restrict__ trans,
    float* __restrict__ out)
{
  __shared__ unsigned char bps[SDIM][TDIM];
  const int b = blockIdx.x;
  const int lane = threadIdx.x;
  const int curr = lane & 31;
  const float* __restrict__ em = g_em;

  float tr[TDIM];
#pragma unroll
  for (int p = 0; p < TDIM; ++p) tr[p] = trans[curr * TDIM + p];

  // int32/int64-robust lens read (values >= 1, so high word of an int64 is 0)
  int len;
  {
    const int* p32 = lens;
    if (p32[1] == 0) {
      len = (int)((const long long*)lens)[b];
    } else {
      len = p32[b];
    }
  }

  float fv = em[b * TDIM + curr];
  float em_next = em[(size_t)BDIM * TDIM + b * TDIM + curr];

  for (int t = 1; t < SDIM; ++t) {
    float emt = em_next;
    int tn = (t < SDIM - 1) ? t + 1 : t;
    em_next = em[(size_t)tn * BDIM * TDIM + b * TDIM + curr];

    float s[TDIM];
#pragma unroll
    for (int p = 0; p < TDIM; ++p)
      s[p] = __shfl(fv, p, 64) + tr[p];

    // blocked max chains, lowest-index-wins tie-break
    float c0 = s[0], c1 = s[8], c2 = s[16], c3 = s[24];
    int i0 = 0, i1 = 8, i2 = 16, i3 = 24;
#pragma unroll
    for (int q = 1; q < 8; ++q) {
      if (s[q]      > c0) { c0 = s[q];      i0 = q; }
      if (s[8 + q]  > c1) { c1 = s[8 + q];  i1 = 8 + q; }
      if (s[16 + q] > c2) { c2 = s[16 + q]; i2 = 16 + q; }
      if (s[24 + q] > c3) { c3 = s[24 + q]; i3 = 24 + q; }
    }
    if (c1 > c0) { c0 = c1; i0 = i1; }
    if (c2 > c0) { c0 = c2; i0 = i2; }
    if (c3 > c0) { c0 = c3; i0 = i3; }

    const bool active = (t < len);
    float nfv = c0 + emt;
    fv = active ? nfv : fv;
    int bp = active ? i0 : curr;
    if (lane < TDIM) bps[t][curr] = (unsigned char)bp;
  }

  // argmax over lanes 0..31, lowest index wins ties
  float bs = fv;
  int bi = curr;
#pragma unroll
  for (int off = 16; off > 0; off >>= 1) {
    float os = __shfl_down(bs, off, 32);
    int oi = __shfl_down(bi, off, 32);
    if (os > bs || (os == bs && oi < bi)) { bs = os; bi = oi; }
  }

  __syncthreads();

  if (lane == 0) {
    out[(size_t)SDIM * BDIM + b] = bs;                 // best_score (f32)
    int tag = bi;
    out[(size_t)(SDIM - 1) * BDIM + b] = (float)tag;   // paths (f32-encoded ints)
    for (int t = SDIM - 1; t >= 1; --t) {
      tag = bps[t][tag];
      out[(size_t)(t - 1) * BDIM + b] = (float)tag;
    }
  }
}

// ---------------- host ----------------
static int find_by_size(const int* in_sizes, int n_in, int sz, int fb) {
  for (int i = 0; i < n_in; ++i) if (in_sizes[i] == sz) return i;
  return fb;
}

extern "C" void kernel_launch(void* const* d_in, const int* in_sizes, int n_in,
                              void* d_out, int out_size, void* d_ws, size_t ws_size,
                              hipStream_t stream) {
  const int i_hidden = find_by_size(in_sizes, n_in, SDIM * BDIM * HDIM, 0);
  const int i_lens   = find_by_size(in_sizes, n_in, BDIM, 1);
  const int i_W1     = find_by_size(in_sizes, n_in, HDIM * HDIM, 3);
  const int i_b1     = find_by_size(in_sizes, n_in, HDIM, 4);
  const int i_W2     = find_by_size(in_sizes, n_in, HDIM * TDIM, 5);
  const int i_b2     = find_by_size(in_sizes, n_in, TDIM, 6);
  const int i_tr     = find_by_size(in_sizes, n_in, TDIM * TDIM, 7);

  const float* hidden = (const float*)d_in[i_hidden];
  const int*   lens   = (const int*)d_in[i_lens];
  const float* W1     = (const float*)d_in[i_W1];
  const float* b1     = (const float*)d_in[i_b1];
  const float* W2     = (const float*)d_in[i_W2];
  const float* b2     = (const float*)d_in[i_b2];
  const float* trans  = (const float*)d_in[i_tr];
  float* out = (float*)d_out;

  emis_kernel<<<(SDIM * BDIM) / BM, 256, 0, stream>>>(hidden, W1, b1, W2, b2);
  viterbi_kernel<<<BDIM, 64, 0, stream>>>(lens, trans, out);
}